// Round 6
// baseline (185.245 us; speedup 1.0000x reference)
//
#include <hip/hip_runtime.h>

// StochasticPool2D eval-mode: out = sum(w^2)/sum(w) over non-overlapping 2x2
// windows of relu(x); windows summing to 0 produce 0.
// x: [64, 256, 112, 112] f32  ->  out: [64, 256, 56, 56] f32
//
// R5: R4's chunked-LDS pipeline, but with RAW barriers + manual lgkmcnt
// waits instead of __syncthreads(). __syncthreads() makes hipcc emit
// `s_waitcnt vmcnt(0)` before s_barrier, draining the register-prefetch
// loads at the barrier and re-creating the read bubble R4 tried to remove.
// Barrier correctness here only needs LDS ordering:
//   - writes visible before cross-wave reads  -> lgkmcnt(0) + s_barrier
//   - reads done before next-iter overwrite   -> lgkmcnt(0) + s_barrier
// The in-flight global loads are thread-private register destinations; the
// compiler's own vmcnt tracking waits at their first use (next ds_write).
// Grid 1024 = exactly 4 blocks/CU resident (28 KB LDS), 28 chunks each,
// uniform -- no residency tail.

typedef float v4f __attribute__((ext_vector_type(4)));

#define NCHUNK 28672u
#define CH_IN4 1792u   // v4f per input chunk  (64 rows x 112 f32 = 28 KB)
#define CH_OUT 1792u   // f32 per output chunk (32 rows x 56)
#define GRID   1024u
#define ITERS  28u     // NCHUNK / GRID, exact

__device__ __forceinline__ float pool1(float x0, float x1, float y0, float y1) {
    float a0 = fmaxf(x0, 0.f), a1 = fmaxf(x1, 0.f);
    float b0 = fmaxf(y0, 0.f), b1 = fmaxf(y1, 0.f);
    float s = (a0 + a1) + (b0 + b1);
    float q = (a0 * a0 + a1 * a1) + (b0 * b0 + b1 * b1);
    return (s > 0.f) ? q * __builtin_amdgcn_rcpf(s) : 0.f;
}

__global__ __launch_bounds__(256) void stoch_pool2d_kernel(
    const float* __restrict__ in, float* __restrict__ out) {
    __shared__ v4f lds[CH_IN4];           // 28 KB -> 4 blocks/CU at grid 1024
    const unsigned int t = threadIdx.x;

    unsigned int c = blockIdx.x;

    // Prologue: load first chunk into registers.
    v4f r[7];
    {
        const v4f* src = reinterpret_cast<const v4f*>(in) + (size_t)c * CH_IN4;
#pragma unroll
        for (int i = 0; i < 7; ++i)
            r[i] = __builtin_nontemporal_load(src + (i * 256u + t));
    }

    for (unsigned int it = 0; it < ITERS; ++it) {
        // Drain regs -> LDS. Compiler inserts the vmcnt wait for r[] here;
        // those loads were issued a full chunk ago, so it's free.
#pragma unroll
        for (int i = 0; i < 7; ++i)
            lds[i * 256u + t] = r[i];

        // Prefetch next chunk into regs. With the raw barrier below these
        // loads stay in flight through the whole compute phase.
        v4f nxt[7];
        if (it + 1u < ITERS) {
            const v4f* src =
                reinterpret_cast<const v4f*>(in) + (size_t)(c + GRID) * CH_IN4;
#pragma unroll
            for (int i = 0; i < 7; ++i)
                nxt[i] = __builtin_nontemporal_load(src + (i * 256u + t));
        }

        // LDS-only fence + raw barrier (NO vmcnt drain).
        asm volatile("s_waitcnt lgkmcnt(0)" ::: "memory");
        __builtin_amdgcn_s_barrier();

        // Compute: each thread-iter builds one output v4f (4 windows).
        // 448 v4f per chunk: iter0 all threads, iter1 t<192 (wave 3 idle).
        float* dst = out + (size_t)c * CH_OUT;
#pragma unroll
        for (unsigned int i = 0; i < 2; ++i) {
            unsigned int o4 = i * 256u + t;
            if (o4 < 448u) {
                unsigned int orow = o4 / 14u;          // output row in chunk
                unsigned int oc4  = o4 - orow * 14u;   // v4f col in out row
                unsigned int base = orow * 56u + oc4 * 2u;  // v4f idx, top row
                v4f t0 = lds[base];
                v4f t1 = lds[base + 1u];
                v4f b0 = lds[base + 28u];              // +112 f32 = next row
                v4f b1 = lds[base + 29u];
                v4f v;
                v.x = pool1(t0.x, t0.y, b0.x, b0.y);
                v.y = pool1(t0.z, t0.w, b0.z, b0.w);
                v.z = pool1(t1.x, t1.y, b1.x, b1.y);
                v.w = pool1(t1.z, t1.w, b1.z, b1.w);
                __builtin_nontemporal_store(v, reinterpret_cast<v4f*>(dst) + o4);
            }
        }

        // My ds_reads are done (results consumed into regs) before others may
        // overwrite LDS: lgkm drain + raw barrier again. Output NT stores and
        // prefetch loads remain in flight.
        asm volatile("s_waitcnt lgkmcnt(0)" ::: "memory");
        __builtin_amdgcn_s_barrier();

#pragma unroll
        for (int i = 0; i < 7; ++i) r[i] = nxt[i];
        c += GRID;
    }
}

extern "C" void kernel_launch(void* const* d_in, const int* in_sizes, int n_in,
                              void* d_out, int out_size, void* d_ws, size_t ws_size,
                              hipStream_t stream) {
    const float* x = (const float*)d_in[0];
    float* out = (float*)d_out;

    stoch_pool2d_kernel<<<GRID, 256, 0, stream>>>(x, out);
}